// Round 1
// baseline (369.019 us; speedup 1.0000x reference)
//
#include <hip/hip_runtime.h>
#include <cmath>

typedef __bf16 bf16x8 __attribute__((ext_vector_type(8)));
typedef float  f32x4  __attribute__((ext_vector_type(4)));

// GEMM config: BM=256 (=M), BN=64, BK=64, 512 threads (8 waves)
#define NK 64           // 4096 / 64
#define LDS_W_OFF 32768 // A tile: 256*128B = 32KB; W tile: 64*128B = 8KB
#define BUFB 40960      // one buffer = 40KB; double buffered = 80KB

__device__ __forceinline__ int swz(int row, int byteInRow) {
    // XOR-swizzle: spreads the 128B row stride across banks (G4 / T2)
    return row * 128 + (byteInRow ^ ((row & 7) << 4));
}

__device__ __forceinline__ bf16x8 cvt8(f32x4 a, f32x4 b) {
    bf16x8 r;
    r[0] = (__bf16)a[0]; r[1] = (__bf16)a[1]; r[2] = (__bf16)a[2]; r[3] = (__bf16)a[3];
    r[4] = (__bf16)b[0]; r[5] = (__bf16)b[1]; r[6] = (__bf16)b[2]; r[7] = (__bf16)b[3];
    return r;
}

// MODE 0: gates GEMM. A = concat(cat,x,hid) selected per K-tile, W = 4 gate mats.
// MODE 1: output GEMM. A = Ahid (lda 4096), W = W0 only.
template <int MODE>
__global__ __launch_bounds__(512, 2)
void gemm_bf16(const float* __restrict__ Acat, const float* __restrict__ Ax,
               const float* __restrict__ Ahid,
               const float* __restrict__ W0, const float* __restrict__ W1,
               const float* __restrict__ W2, const float* __restrict__ W3,
               const float* __restrict__ B0, const float* __restrict__ B1,
               const float* __restrict__ B2, const float* __restrict__ B3,
               float* __restrict__ out, int ldout)
{
    __shared__ __align__(16) unsigned char lds[2 * BUFB];

    const int tid  = threadIdx.x;
    const int lane = tid & 63;
    const int wid  = tid >> 6;     // 0..7
    const int l15  = lane & 15;
    const int l4   = lane >> 4;    // 0..3
    const int wr   = wid >> 1;     // wave row: 0..3 -> 64 M-rows each
    const int wc   = wid & 1;      // wave col: 0..1 -> 32 N-cols each

    const int n0 = blockIdx.x * 64;
    const float* Wsrc; const float* Bsrc; int wn0;
    if (MODE == 0) {
        int gate = n0 >> 12;
        Wsrc = (gate == 0) ? W0 : (gate == 1) ? W1 : (gate == 2) ? W2 : W3;
        Bsrc = (gate == 0) ? B0 : (gate == 1) ? B1 : (gate == 2) ? B2 : B3;
        wn0  = n0 & 4095;
    } else {
        Wsrc = W0; Bsrc = B0; wn0 = n0;
    }

    f32x4 areg[8];   // A: 4 chunks of 32B per thread (256 rows x 64 f32 / 512 thr)
    f32x4 wreg[2];   // W: 1 chunk of 32B per thread (64 rows x 64 f32 / 512 thr)
    f32x4 acc[4][2] = {};

    auto load_tile = [&](int ks) {
        const int k0 = ks * 64;
        const float* asrc; int lda, acol;
        if (MODE == 0) {
            if (k0 < 512)       { asrc = Acat; lda = 512;  acol = k0; }
            else if (k0 < 2048) { asrc = Ax;   lda = 1536; acol = k0 - 512; }
            else                { asrc = Ahid; lda = 2048; acol = k0 - 2048; }
        } else { asrc = Ahid; lda = 4096; acol = k0; }
        #pragma unroll
        for (int i = 0; i < 4; ++i) {
            int fid = tid + i * 512;
            int row = fid >> 3, c8 = fid & 7;
            const float* p = asrc + (size_t)row * lda + acol + c8 * 8;
            areg[2 * i]     = *(const f32x4*)p;
            areg[2 * i + 1] = *(const f32x4*)(p + 4);
        }
        {
            int row = tid >> 3, c8 = tid & 7;
            const float* p = Wsrc + (size_t)(wn0 + row) * 4096 + k0 + c8 * 8;
            wreg[0] = *(const f32x4*)p;
            wreg[1] = *(const f32x4*)(p + 4);
        }
    };

    auto store_tile = [&](int buf) {
        unsigned char* base = lds + buf * BUFB;
        #pragma unroll
        for (int i = 0; i < 4; ++i) {
            int fid = tid + i * 512;
            int row = fid >> 3, c8 = fid & 7;
            *(bf16x8*)(base + swz(row, c8 * 16)) = cvt8(areg[2 * i], areg[2 * i + 1]);
        }
        {
            int row = tid >> 3, c8 = tid & 7;
            *(bf16x8*)(base + LDS_W_OFF + swz(row, c8 * 16)) = cvt8(wreg[0], wreg[1]);
        }
    };

    load_tile(0);
    store_tile(0);
    __syncthreads();

    for (int ks = 0; ks < NK; ++ks) {
        const int cur = ks & 1;
        unsigned char* cbase = lds + cur * BUFB;
        if (ks + 1 < NK) load_tile(ks + 1);   // next-tile loads in flight over MFMA
        #pragma unroll
        for (int kk = 0; kk < 2; ++kk) {
            bf16x8 af[4], bw[2];
            #pragma unroll
            for (int m = 0; m < 4; ++m) {
                int row = wr * 64 + m * 16 + l15;
                af[m] = *(const bf16x8*)(cbase + swz(row, kk * 64 + l4 * 16));
            }
            #pragma unroll
            for (int n = 0; n < 2; ++n) {
                int row = wc * 32 + n * 16 + l15;
                bw[n] = *(const bf16x8*)(cbase + LDS_W_OFF + swz(row, kk * 64 + l4 * 16));
            }
            #pragma unroll
            for (int m = 0; m < 4; ++m)
                #pragma unroll
                for (int n = 0; n < 2; ++n)
                    acc[m][n] = __builtin_amdgcn_mfma_f32_16x16x32_bf16(af[m], bw[n], acc[m][n], 0, 0, 0);
        }
        if (ks + 1 < NK) store_tile(cur ^ 1);
        __syncthreads();
    }

    // epilogue: C/D map col=lane&15, row=(lane>>4)*4+j  [m89-verified]
    #pragma unroll
    for (int n = 0; n < 2; ++n) {
        int col = wc * 32 + n * 16 + l15;
        float bias = Bsrc[wn0 + col];
        #pragma unroll
        for (int m = 0; m < 4; ++m) {
            int row = wr * 64 + m * 16 + l4 * 4;
            f32x4 v = acc[m][n];
            #pragma unroll
            for (int j = 0; j < 4; ++j)
                out[(size_t)(row + j) * ldout + n0 + col] = v[j] + bias;
        }
    }
}

__global__ __launch_bounds__(256)
void lstm_elem(const float* __restrict__ z, const float* __restrict__ cell,
               float* __restrict__ cnew, float* __restrict__ hnew)
{
    int t  = blockIdx.x * 256 + threadIdx.x;   // 0..262143 (B*C/4)
    int b  = t >> 10, c4 = t & 1023;
    const float* zrow = z + (size_t)b * 16384 + c4 * 4;
    f32x4 vf = *(const f32x4*)(zrow);
    f32x4 vi = *(const f32x4*)(zrow + 4096);
    f32x4 vg = *(const f32x4*)(zrow + 8192);
    f32x4 vo = *(const f32x4*)(zrow + 12288);
    f32x4 vc = *(const f32x4*)(cell + (size_t)b * 4096 + c4 * 4);
    f32x4 rc, rh;
    #pragma unroll
    for (int j = 0; j < 4; ++j) {
        float f = 1.0f / (1.0f + __expf(-vf[j]));
        float i = 1.0f / (1.0f + __expf(-vi[j]));
        float g = tanhf(vg[j]);
        float o = 1.0f / (1.0f + __expf(-vo[j]));
        float cn = f * vc[j] + i * g;
        rc[j] = cn;
        rh[j] = o * tanhf(cn);
    }
    *(f32x4*)(cnew + (size_t)b * 4096 + c4 * 4) = rc;
    *(f32x4*)(hnew + (size_t)b * 4096 + c4 * 4) = rh;
}

__global__ __launch_bounds__(256)
void logsoftmax_inplace(float* __restrict__ out)
{
    const int b   = blockIdx.x;
    float* row    = out + (size_t)b * 32000;
    const int tid = threadIdx.x;
    __shared__ float red[4];

    float m = -1e30f;
    for (int i = tid; i < 8000; i += 256) {
        f32x4 v = *(const f32x4*)(row + i * 4);
        m = fmaxf(fmaxf(fmaxf(m, v[0]), v[1]), fmaxf(v[2], v[3]));
    }
    #pragma unroll
    for (int s = 32; s; s >>= 1) m = fmaxf(m, __shfl_xor(m, s));
    if ((tid & 63) == 0) red[tid >> 6] = m;
    __syncthreads();
    m = fmaxf(fmaxf(red[0], red[1]), fmaxf(red[2], red[3]));

    float s = 0.0f;
    for (int i = tid; i < 8000; i += 256) {
        f32x4 v = *(const f32x4*)(row + i * 4);
        s += __expf(v[0] - m) + __expf(v[1] - m) + __expf(v[2] - m) + __expf(v[3] - m);
    }
    #pragma unroll
    for (int st = 32; st; st >>= 1) s += __shfl_xor(s, st);
    __syncthreads();
    if ((tid & 63) == 0) red[tid >> 6] = s;
    __syncthreads();
    s = red[0] + red[1] + red[2] + red[3];
    float lse = m + logf(s);

    for (int i = tid; i < 8000; i += 256) {
        f32x4 v = *(const f32x4*)(row + i * 4);
        v[0] -= lse; v[1] -= lse; v[2] -= lse; v[3] -= lse;
        *(f32x4*)(row + i * 4) = v;
    }
}

extern "C" void kernel_launch(void* const* d_in, const int* in_sizes, int n_in,
                              void* d_out, int out_size, void* d_ws, size_t ws_size,
                              hipStream_t stream)
{
    const float* cat  = (const float*)d_in[0];
    const float* x    = (const float*)d_in[1];
    const float* hid  = (const float*)d_in[2];
    const float* cell = (const float*)d_in[3];
    const float* Wf   = (const float*)d_in[4];
    const float* bf   = (const float*)d_in[5];
    const float* Wi   = (const float*)d_in[6];
    const float* bi   = (const float*)d_in[7];
    const float* Wc   = (const float*)d_in[8];
    const float* bc   = (const float*)d_in[9];
    const float* Wo   = (const float*)d_in[10];
    const float* bo   = (const float*)d_in[11];
    const float* Wout = (const float*)d_in[12];
    const float* bout = (const float*)d_in[13];
    float* out = (float*)d_out;

    // d_out layout: [logits 256x32000 | cell_new 256x4096 | hidden_new 256x4096]
    // z (256x16384 fp32 = 16MB) transiently lives in the logits region (32MB):
    // written by gemm<0>, consumed by lstm_elem, then overwritten by gemm<1>.
    float* z    = out;
    float* cnew = out + 8192000;
    float* hnew = out + 9240576;

    // 1) z = xc @ [Wf;Wi;Wc;Wo]^T + b   (N=16384 -> 256 blocks)
    gemm_bf16<0><<<256, 512, 0, stream>>>(cat, x, hid, Wf, Wi, Wc, Wo,
                                          bf, bi, bc, bo, z, 16384);
    // 2) gates -> cell_new, hidden_new
    lstm_elem<<<1024, 256, 0, stream>>>(z, cell, cnew, hnew);
    // 3) logits = hidden_new @ Wout^T + bout   (N=32000 -> 500 blocks)
    gemm_bf16<1><<<500, 512, 0, stream>>>(nullptr, nullptr, hnew, Wout, Wout, Wout, Wout,
                                          bout, bout, bout, bout, out, 32000);
    // 4) log_softmax rows in place
    logsoftmax_inplace<<<256, 256, 0, stream>>>(out);
}

// Round 2
// 285.699 us; speedup vs baseline: 1.2916x; 1.2916x over previous
//
#include <hip/hip_runtime.h>
#include <cmath>

typedef __bf16 bf16x8 __attribute__((ext_vector_type(8)));
typedef float  f32x4  __attribute__((ext_vector_type(4)));

// GEMM config: BM=256 (=M, full batch -> each W row fetched exactly once),
// BN=64, BK=64, 512 threads (8 waves), double-buffered LDS.
#define NK 64            // 4096 / 64
#define ATILE 32768      // A tile: 256 rows * 128B (bf16, swizzled)
#define LDS_W_OFF 32768  // W tile after A tile
#define BUFB 40960       // A 32KB + W 8KB; x2 buffers = 80KB/block (2 blocks/CU)

#define GLOAD_LDS16(g, l)                                                    \
    __builtin_amdgcn_global_load_lds(                                        \
        (const __attribute__((address_space(1))) unsigned int*)(g),          \
        (__attribute__((address_space(3))) unsigned int*)(l), 16, 0, 0)

__device__ __forceinline__ int swz(int row, int byteInRow) {
    // XOR-swizzle: spreads the 128B row stride across banks (G4 / T2)
    return row * 128 + (byteInRow ^ ((row & 7) << 4));
}

__device__ __forceinline__ bf16x8 cvt8(f32x4 a, f32x4 b) {
    bf16x8 r;
    r[0] = (__bf16)a[0]; r[1] = (__bf16)a[1]; r[2] = (__bf16)a[2]; r[3] = (__bf16)a[3];
    r[4] = (__bf16)b[0]; r[5] = (__bf16)b[1]; r[6] = (__bf16)b[2]; r[7] = (__bf16)b[3];
    return r;
}

// Build A0 = concat(cat,x,hid) as bf16, K-tiled (64-col tiles) + swizzled, so
// the GEMM can global_load_lds it with a linear LDS dest (rule #21).
__global__ __launch_bounds__(256)
void prep_xc(const float* __restrict__ cat, const float* __restrict__ x,
             const float* __restrict__ hid, unsigned char* __restrict__ A0)
{
    int id  = blockIdx.x * 256 + threadIdx.x;   // 0..131071 (256*4096/8)
    int row = id >> 9, col = (id & 511) * 8;
    const float* src = (col < 512)  ? cat + (size_t)row * 512 + col
                     : (col < 2048) ? x   + (size_t)row * 1536 + (col - 512)
                                    : hid + (size_t)row * 2048 + (col - 2048);
    f32x4 a = *(const f32x4*)src, b = *(const f32x4*)(src + 4);
    int ks = col >> 6, c8 = (col & 63) >> 3;
    *(bf16x8*)(A0 + (size_t)ks * ATILE + swz(row, c8 * 16)) = cvt8(a, b);
}

// MODE 0: gates GEMM (W select by N-range). MODE 1: vocab GEMM (W0 only).
template <int MODE>
__global__ __launch_bounds__(512, 4)
void gemm_bf16(const unsigned char* __restrict__ At,
               const float* __restrict__ W0, const float* __restrict__ W1,
               const float* __restrict__ W2, const float* __restrict__ W3,
               const float* __restrict__ B0, const float* __restrict__ B1,
               const float* __restrict__ B2, const float* __restrict__ B3,
               float* __restrict__ out, int ldout)
{
    __shared__ __align__(16) unsigned char lds[2 * BUFB];

    const int tid  = threadIdx.x;
    const int lane = tid & 63;
    const int wid  = tid >> 6;     // 0..7
    const int l15  = lane & 15;
    const int l4   = lane >> 4;    // 0..3
    const int wr   = wid >> 1;     // wave row: 0..3 -> 64 M-rows each
    const int wc   = wid & 1;      // wave col: 0..1 -> 32 N-cols each

    const int n0 = blockIdx.x * 64;
    const float* Wsrc; const float* Bsrc; int wn0;
    if (MODE == 0) {
        int g = n0 >> 12;
        Wsrc = (g == 0) ? W0 : (g == 1) ? W1 : (g == 2) ? W2 : W3;
        Bsrc = (g == 0) ? B0 : (g == 1) ? B1 : (g == 2) ? B2 : B3;
        wn0  = n0 & 4095;
    } else {
        Wsrc = W0; Bsrc = B0; wn0 = n0;
    }

    f32x4 wreg[2];
    f32x4 acc[4][2] = {};

    const int wrow = tid >> 3, wc8 = tid & 7;   // W staging coords (64 rows x 8 chunks)
    const float* wbase = Wsrc + (size_t)(wn0 + wrow) * 4096 + wc8 * 8;

    auto issueA = [&](int ks, int buf) {
        // A tile image in ws == desired LDS image; wave-uniform dest + lane*16
        const unsigned char* src = At + (size_t)ks * ATILE + wid * 4096 + lane * 16;
        unsigned char* dst = lds + buf * BUFB + wid * 4096;
        #pragma unroll
        for (int i = 0; i < 4; ++i)
            GLOAD_LDS16(src + i * 1024, dst + i * 1024);
    };
    auto loadW  = [&](int ks) {
        const float* p = wbase + ks * 64;
        wreg[0] = *(const f32x4*)p;
        wreg[1] = *(const f32x4*)(p + 4);
    };
    auto storeW = [&](int buf) {
        *(bf16x8*)(lds + buf * BUFB + LDS_W_OFF + swz(wrow, wc8 * 16)) = cvt8(wreg[0], wreg[1]);
    };

    issueA(0, 0);
    loadW(0);
    storeW(0);
    __syncthreads();   // compiler drains vmcnt+lgkmcnt here

    for (int ks = 0; ks < NK; ++ks) {
        const int cur = ks & 1;
        unsigned char* cbase = lds + cur * BUFB;
        if (ks + 1 < NK) { issueA(ks + 1, cur ^ 1); loadW(ks + 1); }
        #pragma unroll
        for (int kk = 0; kk < 2; ++kk) {
            bf16x8 af[4], bw[2];
            #pragma unroll
            for (int m = 0; m < 4; ++m) {
                int row = wr * 64 + m * 16 + l15;
                af[m] = *(const bf16x8*)(cbase + swz(row, kk * 64 + l4 * 16));
            }
            #pragma unroll
            for (int n = 0; n < 2; ++n) {
                int row = wc * 32 + n * 16 + l15;
                bw[n] = *(const bf16x8*)(cbase + LDS_W_OFF + swz(row, kk * 64 + l4 * 16));
            }
            #pragma unroll
            for (int m = 0; m < 4; ++m)
                #pragma unroll
                for (int n = 0; n < 2; ++n)
                    acc[m][n] = __builtin_amdgcn_mfma_f32_16x16x32_bf16(af[m], bw[n], acc[m][n], 0, 0, 0);
        }
        if (ks + 1 < NK) storeW(cur ^ 1);
        __syncthreads();
    }

    // epilogue: C/D map col=lane&15, row=(lane>>4)*4+j  [m89-verified]
    #pragma unroll
    for (int n = 0; n < 2; ++n) {
        int col = wc * 32 + n * 16 + l15;
        float bias = Bsrc[wn0 + col];
        #pragma unroll
        for (int m = 0; m < 4; ++m) {
            int row = wr * 64 + m * 16 + l4 * 4;
            f32x4 v = acc[m][n];
            #pragma unroll
            for (int j = 0; j < 4; ++j)
                out[(size_t)(row + j) * ldout + n0 + col] = v[j] + bias;
        }
    }
}

// gates -> cell_new/hidden_new (fp32 outputs) + hidden_new bf16 tiled for gemm1
__global__ __launch_bounds__(256)
void lstm_elem(const float* __restrict__ z, const float* __restrict__ cell,
               float* __restrict__ cnew, float* __restrict__ hnew,
               unsigned char* __restrict__ A1)
{
    int id  = blockIdx.x * 256 + threadIdx.x;   // 0..131071
    int row = id >> 9, col = (id & 511) * 8;
    const float* zr = z + (size_t)row * 16384 + col;
    f32x4 vf[2] = { *(const f32x4*)(zr),         *(const f32x4*)(zr + 4) };
    f32x4 vi[2] = { *(const f32x4*)(zr + 4096),  *(const f32x4*)(zr + 4100) };
    f32x4 vg[2] = { *(const f32x4*)(zr + 8192),  *(const f32x4*)(zr + 8196) };
    f32x4 vo[2] = { *(const f32x4*)(zr + 12288), *(const f32x4*)(zr + 12292) };
    const float* cr = cell + (size_t)row * 4096 + col;
    f32x4 vc[2] = { *(const f32x4*)cr, *(const f32x4*)(cr + 4) };
    f32x4 rc[2], rh[2];
    bf16x8 hb;
    #pragma unroll
    for (int h = 0; h < 2; ++h)
        #pragma unroll
        for (int j = 0; j < 4; ++j) {
            float f = 1.0f / (1.0f + __expf(-vf[h][j]));
            float i = 1.0f / (1.0f + __expf(-vi[h][j]));
            float g = tanhf(vg[h][j]);
            float o = 1.0f / (1.0f + __expf(-vo[h][j]));
            float cn = f * vc[h][j] + i * g;
            float hn = o * tanhf(cn);
            rc[h][j] = cn; rh[h][j] = hn;
            hb[h * 4 + j] = (__bf16)hn;
        }
    float* cd = cnew + (size_t)row * 4096 + col;
    float* hd = hnew + (size_t)row * 4096 + col;
    *(f32x4*)cd = rc[0]; *(f32x4*)(cd + 4) = rc[1];
    *(f32x4*)hd = rh[0]; *(f32x4*)(hd + 4) = rh[1];
    int ks = col >> 6, c8 = (col & 63) >> 3;
    *(bf16x8*)(A1 + (size_t)ks * ATILE + swz(row, c8 * 16)) = hb;
}

// in-place log_softmax, one block per row; online (m,s) then write pass
__global__ __launch_bounds__(256)
void logsoftmax_inplace(float* __restrict__ out)
{
    float* row    = out + (size_t)blockIdx.x * 32000;
    const int tid = threadIdx.x;
    __shared__ float redm[4], reds[4];

    float m = -1e30f, s = 0.0f;
    for (int i = tid; i < 8000; i += 256) {
        f32x4 v = *(const f32x4*)(row + i * 4);
        float t = fmaxf(fmaxf(v[0], v[1]), fmaxf(v[2], v[3]));
        float nm = fmaxf(m, t);
        s = s * __expf(m - nm) + __expf(v[0] - nm) + __expf(v[1] - nm)
                               + __expf(v[2] - nm) + __expf(v[3] - nm);
        m = nm;
    }
    #pragma unroll
    for (int off = 32; off; off >>= 1) {
        float om = __shfl_xor(m, off), os = __shfl_xor(s, off);
        float nm = fmaxf(m, om);
        s = s * __expf(m - nm) + os * __expf(om - nm);
        m = nm;
    }
    if ((tid & 63) == 0) { redm[tid >> 6] = m; reds[tid >> 6] = s; }
    __syncthreads();
    {
        float M = fmaxf(fmaxf(redm[0], redm[1]), fmaxf(redm[2], redm[3]));
        float S = reds[0] * __expf(redm[0] - M) + reds[1] * __expf(redm[1] - M)
                + reds[2] * __expf(redm[2] - M) + reds[3] * __expf(redm[3] - M);
        m = M; s = S;
    }
    float lse = m + logf(s);

    for (int i = tid; i < 8000; i += 256) {
        f32x4 v = *(const f32x4*)(row + i * 4);
        v[0] -= lse; v[1] -= lse; v[2] -= lse; v[3] -= lse;
        *(f32x4*)(row + i * 4) = v;
    }
}

extern "C" void kernel_launch(void* const* d_in, const int* in_sizes, int n_in,
                              void* d_out, int out_size, void* d_ws, size_t ws_size,
                              hipStream_t stream)
{
    const float* cat  = (const float*)d_in[0];
    const float* x    = (const float*)d_in[1];
    const float* hid  = (const float*)d_in[2];
    const float* cell = (const float*)d_in[3];
    const float* Wf   = (const float*)d_in[4];
    const float* bf   = (const float*)d_in[5];
    const float* Wi   = (const float*)d_in[6];
    const float* bi   = (const float*)d_in[7];
    const float* Wc   = (const float*)d_in[8];
    const float* bc   = (const float*)d_in[9];
    const float* Wo   = (const float*)d_in[10];
    const float* bo   = (const float*)d_in[11];
    const float* Wout = (const float*)d_in[12];
    const float* bout = (const float*)d_in[13];
    float* out = (float*)d_out;

    // ws layout: A0 bf16-tiled xc (2MB) | A1 bf16-tiled hidden_new (2MB) | z fp32 (16MB)
    unsigned char* A0 = (unsigned char*)d_ws;
    unsigned char* A1 = A0 + (size_t)64 * ATILE;
    float*         z  = (float*)(A1 + (size_t)64 * ATILE);

    // d_out layout: [logits 256x32000 | cell_new 256x4096 | hidden_new 256x4096]
    float* cnew = out + 8192000;
    float* hnew = out + 9240576;

    // 0) xc -> bf16 tiled/swizzled
    prep_xc<<<512, 256, 0, stream>>>(cat, x, hid, A0);
    // 1) z = xc @ [Wf;Wi;Wc;Wo]^T + b   (N=16384 -> 256 blocks)
    gemm_bf16<0><<<256, 512, 0, stream>>>(A0, Wf, Wi, Wc, Wo, bf, bi, bc, bo, z, 16384);
    // 2) gates -> cell_new, hidden_new (+ bf16 tiled hidden for gemm1)
    lstm_elem<<<512, 256, 0, stream>>>(z, cell, cnew, hnew, A1);
    // 3) logits = hidden_new @ Wout^T + bout   (N=32000 -> 500 blocks)
    gemm_bf16<1><<<500, 512, 0, stream>>>(A1, Wout, Wout, Wout, Wout,
                                          bout, bout, bout, bout, out, 32000);
    // 4) log_softmax rows in place
    logsoftmax_inplace<<<256, 256, 0, stream>>>(out);
}